// Round 1
// baseline (209.962 us; speedup 1.0000x reference)
//
#include <hip/hip_runtime.h>
#include <hip/hip_fp16.h>

#define FDIM 128
#define HEADS 4
#define CD 32
#define BM 64

typedef __attribute__((ext_vector_type(8))) short bfrag;   // 8 bf16 (4 VGPRs)
typedef __attribute__((ext_vector_type(4))) float ffrag;   // 4 f32 accum

static __device__ __forceinline__ unsigned short f2bf(float v) {
    unsigned u = __float_as_uint(v);
    u += 0x7FFF + ((u >> 16) & 1);          // round-nearest-even
    return (unsigned short)(u >> 16);
}
static __device__ __forceinline__ float bf2f(unsigned short u) {
    return __uint_as_float(((unsigned)u) << 16);
}

// K0: split W into bf16 hi/lo and transpose to [n][k] so MFMA B-frags are
// contiguous-k 16B loads.  64KB output, L2-resident for the whole GEMM.
__global__ __launch_bounds__(256) void k_wsplit(const float* __restrict__ w,
                                                unsigned short* __restrict__ wt_hi,
                                                unsigned short* __restrict__ wt_lo)
{
    int i = blockIdx.x * 256 + threadIdx.x;      // 16384 elements, coalesced read
    float v = w[i];
    unsigned short h = f2bf(v);
    float r = v - bf2f(h);
    int k = i >> 7, n = i & 127;
    wt_hi[n * FDIM + k] = h;
    wt_lo[n * FDIM + k] = f2bf(r);
}

// K1: MFMA GEMM (split bf16: hi*hi + hi*lo + lo*hi ~= fp32) + logits.
// A-frags straight from global x (dense per-wave 16rows x 64B), no x staging.
// Epilogue (xwh store, logits via LDS round-trip) semantics unchanged.
__global__ __launch_bounds__(256) void k_gemm(const float* __restrict__ x,
                                              const unsigned short* __restrict__ wt_hi,
                                              const unsigned short* __restrict__ wt_lo,
                                              const float* __restrict__ att,
                                              unsigned short* __restrict__ xwh,
                                              float* __restrict__ a_src,
                                              float* __restrict__ a_dst,
                                              float4* __restrict__ zero_base,
                                              int nz4, int N)
{
    __shared__ float accs[BM * 132];     // 64 rows x 128 cols, stride 132 (33.8KB)
    __shared__ float attl[HEADS * 2 * CD];
    int t = threadIdx.x;
    int row0 = blockIdx.x * BM;
    // zero accumulators for later kernels (independent of GEMM work)
    for (int i = blockIdx.x * 256 + t; i < nz4; i += gridDim.x * 256)
        zero_base[i] = make_float4(0.f, 0.f, 0.f, 0.f);
    attl[t] = att[t];

    int l = t & 63, wv = t >> 6;         // wave id 0..3 -> rows wv*16..wv*16+15
    int la = l & 15, lr = l >> 4;        // A/B free-dim lane, k-chunk group
    int arow = row0 + wv * 16 + la;      // x row this lane feeds
    bool aval = arow < N;
    const float* xbase = x + (size_t)arow * FDIM + lr * 8;

    ffrag acc[8] = {};                   // 8 col-tiles x 4 f32
#pragma unroll
    for (int ks = 0; ks < 4; ks++) {     // K = 128 = 4 x 32
        float xv[8] = {0.f, 0.f, 0.f, 0.f, 0.f, 0.f, 0.f, 0.f};
        if (aval) {
            float4 f0 = *(const float4*)(xbase + ks * 32);
            float4 f1 = *(const float4*)(xbase + ks * 32 + 4);
            xv[0] = f0.x; xv[1] = f0.y; xv[2] = f0.z; xv[3] = f0.w;
            xv[4] = f1.x; xv[5] = f1.y; xv[6] = f1.z; xv[7] = f1.w;
        }
        bfrag ah, al;
#pragma unroll
        for (int j = 0; j < 8; j++) {
            unsigned short h = f2bf(xv[j]);
            ah[j] = (short)h;
            al[j] = (short)f2bf(xv[j] - bf2f(h));
        }
        int boff = ks * 32 + lr * 8;
#pragma unroll
        for (int ct = 0; ct < 8; ct++) {
            int o = (ct * 16 + la) * FDIM + boff;
            bfrag bh = *(const bfrag*)(wt_hi + o);
            bfrag bl = *(const bfrag*)(wt_lo + o);
            acc[ct] = __builtin_amdgcn_mfma_f32_16x16x32_bf16(ah, bh, acc[ct], 0, 0, 0);
            acc[ct] = __builtin_amdgcn_mfma_f32_16x16x32_bf16(ah, bl, acc[ct], 0, 0, 0);
            acc[ct] = __builtin_amdgcn_mfma_f32_16x16x32_bf16(al, bh, acc[ct], 0, 0, 0);
        }
    }

    // xwh store, head-interleaved xwh[r*128 + cc*4 + h], packed 8B coalesced.
    // C/D layout: col = ct*16 + la, row = lr*4 + i   (within wave's 16 rows)
#pragma unroll
    for (int i = 0; i < 4; i++) {
        int r = row0 + wv * 16 + lr * 4 + i;
        if (r < N) {
            uint2 pa, pb;
            pa.x = (unsigned)f2bf(acc[0][i]) | ((unsigned)f2bf(acc[2][i]) << 16);
            pa.y = (unsigned)f2bf(acc[4][i]) | ((unsigned)f2bf(acc[6][i]) << 16);
            pb.x = (unsigned)f2bf(acc[1][i]) | ((unsigned)f2bf(acc[3][i]) << 16);
            pb.y = (unsigned)f2bf(acc[5][i]) | ((unsigned)f2bf(acc[7][i]) << 16);
            *(uint2*)&xwh[(size_t)r * FDIM + la * 4] = pa;        // cols {0,32,64,96}+la
            *(uint2*)&xwh[(size_t)r * FDIM + 64 + la * 4] = pb;   // cols {16,48,80,112}+la
        }
    }
    // fp32 acc -> LDS for the logits pass (logical [row][col], stride 132)
#pragma unroll
    for (int ct = 0; ct < 8; ct++)
#pragma unroll
        for (int i = 0; i < 4; i++)
            accs[(wv * 16 + lr * 4 + i) * 132 + ct * 16 + la] = acc[ct][i];
    __syncthreads();
    // logits: 4 lanes per row, lane handles one head (cols h*32..h*32+31)
    int row = t >> 2, h = t & 3;
    const float* ap = &attl[h * 2 * CD];
    const float* xr = &accs[row * 132 + h * CD];
    float s = 0.f, d = 0.f;
#pragma unroll 8
    for (int c = 0; c < CD; c++) { float v = xr[c]; s += v * ap[c]; d += v * ap[CD + c]; }
    int n = row0 + row;
    if (n < N) { a_src[n * 4 + h] = s; a_dst[n * 4 + h] = d; }
}

// K4: seg[row,h] += exp(leaky(...)); 4 adjacent lanes share one 16B sector.
// ealpha stored fp16 (coalesced).
__global__ __launch_bounds__(256) void k_esum(const int* __restrict__ ei, int E,
                                              const float* __restrict__ a_src,
                                              const float* __restrict__ a_dst,
                                              float* __restrict__ seg,
                                              __half* __restrict__ ealpha)
{
    int gid = blockIdx.x * 256 + threadIdx.x;
    if (gid >= E * HEADS) return;
    int e = gid >> 2, h = gid & 3;
    int r = ei[e], cl = ei[E + e];
    float a = a_src[r * 4 + h] + a_dst[cl * 4 + h];
    a = a >= 0.f ? a : 0.2f * a;
    float ex = __expf(a);
    ealpha[gid] = __float2half(ex);
    atomicAdd(&seg[r * 4 + h], ex);
}

// K5: out_acc2[col][c2] += packed fp16 pair — 16 lanes/edge, one
// global_atomic_pk_add_f16 per lane (64 B atomic footprint per edge).
__global__ __launch_bounds__(256) void k_scatter(const int* __restrict__ ei, int E,
                                                 const __half* __restrict__ ealpha,
                                                 const float* __restrict__ seg,
                                                 const unsigned short* __restrict__ xwh,
                                                 __half2* __restrict__ out_acc2)
{
    int t = threadIdx.x;
    int le = t >> 4, c2 = t & 15;        // 16 edges/block
    int e = blockIdx.x * 16 + le;
    if (e >= E) return;
    int r = ei[e], cl = ei[E + e];
    int lane = t & 63;
    float av = 0.f;
    if (c2 < 4) av = 0.25f * __half2float(ealpha[e * 4 + c2]) / (seg[r * 4 + c2] + 1e-16f);
    // xwh[r][2c2..2c2+1][0..3] = 8 bf16 = 16 B
    uint4 q = ((const uint4*)(xwh + (size_t)r * FDIM))[c2];
    float a0 = __shfl(av, (lane & 48) + 0, 64);
    float a1 = __shfl(av, (lane & 48) + 1, 64);
    float a2 = __shfl(av, (lane & 48) + 2, 64);
    float a3 = __shfl(av, (lane & 48) + 3, 64);
    float v0 = a0 * bf2f((unsigned short)(q.x & 0xFFFF)) + a1 * bf2f((unsigned short)(q.x >> 16))
             + a2 * bf2f((unsigned short)(q.y & 0xFFFF)) + a3 * bf2f((unsigned short)(q.y >> 16));
    float v1 = a0 * bf2f((unsigned short)(q.z & 0xFFFF)) + a1 * bf2f((unsigned short)(q.z >> 16))
             + a2 * bf2f((unsigned short)(q.w & 0xFFFF)) + a3 * bf2f((unsigned short)(q.w >> 16));
    unsafeAtomicAdd(&out_acc2[(size_t)cl * 16 + c2], __floats2half2_rn(v0, v1));
}

// K6: out = fp16 out_acc2 + bias
__global__ void k_final(const __half2* __restrict__ out_acc2, const float4* __restrict__ bias,
                        float4* __restrict__ out, int N)
{
    int i = blockIdx.x * 256 + threadIdx.x;
    if (i >= N * 8) return;
    float4 b = bias[i & 7];
    float2 f0 = __half22float2(out_acc2[i * 2]);
    float2 f1 = __half22float2(out_acc2[i * 2 + 1]);
    out[i] = make_float4(f0.x + b.x, f0.y + b.y, f1.x + b.z, f1.y + b.w);
}

extern "C" void kernel_launch(void* const* d_in, const int* in_sizes, int n_in,
                              void* d_out, int out_size, void* d_ws, size_t ws_size,
                              hipStream_t stream)
{
    const float* x    = (const float*)d_in[0];
    const int*   ei   = (const int*)d_in[1];
    const float* w    = (const float*)d_in[2];
    const float* att  = (const float*)d_in[3];
    const float* bias = (const float*)d_in[4];
    float* out = (float*)d_out;
    int N = in_sizes[0] / FDIM;
    int E = in_sizes[1] / 2;

    unsigned short* xwh = (unsigned short*)d_ws;              // N*128 bf16  (12.8 MB)
    float* fws      = (float*)(xwh + (size_t)N * FDIM);
    float* a_src    = fws;                                    // N*4 f32
    float* a_dst    = a_src + (size_t)N * HEADS;              // N*4 f32
    float* seg      = a_dst + (size_t)N * HEADS;              // N*4 f32   (zeroed)
    __half2* out_acc2 = (__half2*)(seg + (size_t)N * HEADS);  // N*16 half2 (zeroed, contig)
    __half* ealpha  = (__half*)(out_acc2 + (size_t)N * 16);   // E*4 fp16
    unsigned short* wt_hi = (unsigned short*)(ealpha + (size_t)E * HEADS); // 128*128 bf16
    unsigned short* wt_lo = wt_hi + FDIM * FDIM;                           // 128*128 bf16

    int nz4 = N * 5;   // (seg: N*4 floats + out_acc2: N*16 half2 == N*16 floats) / 4

    k_wsplit<<<(FDIM * FDIM) / 256, 256, 0, stream>>>(w, wt_hi, wt_lo);
    k_gemm<<<(N + BM - 1) / BM, 256, 0, stream>>>(x, wt_hi, wt_lo, att, xwh, a_src, a_dst,
                                                  (float4*)seg, nz4, N);
    k_esum<<<(E * HEADS + 255) / 256, 256, 0, stream>>>(ei, E, a_src, a_dst, seg, ealpha);
    k_scatter<<<(E + 15) / 16, 256, 0, stream>>>(ei, E, ealpha, seg, xwh, out_acc2);
    k_final<<<(N * 8 + 255) / 256, 256, 0, stream>>>(out_acc2, (const float4*)bias, (float4*)out, N);
}